// Round 8
// baseline (408.714 us; speedup 1.0000x reference)
//
#include <hip/hip_runtime.h>
#include <math.h>

#define NS 64
#define INV2PI  0.15915494309189535f
#define NEGHL2E (-0.72134752044448170f)   // -0.5 * log2(e)

typedef __attribute__((ext_vector_type(4))) float vfloat4;  // native clang vector (nontemporal-store OK)

// P (3x21) flat row-major, exactly as in the reference.
__constant__ float c_P[63] = {
  0.8506508f, 0.0f, 0.5257311f, 0.809017f, 0.5f, 0.309017f, 0.5257311f,
  0.8506508f, 0.0f, 1.0f, 0.0f, 0.0f, 0.809017f, 0.5f, -0.309017f,
  0.8506508f, 0.0f, -0.5257311f, 0.309017f, 0.809017f, -0.5f,
  0.0f, 0.5257311f, -0.8506508f, 0.5f, 0.309017f, -0.809017f, 0.0f, 1.0f,
  0.0f, -0.5257311f, 0.8506508f, 0.0f, -0.309017f, 0.809017f, -0.5f, 0.0f,
  0.5257311f, 0.8506508f, -0.309017f, 0.809017f, 0.5f,
  0.309017f, 0.809017f, 0.5f, 0.5f, 0.309017f, 0.809017f, 0.5f, -0.309017f,
  0.809017f, 0.0f, 0.0f, 1.0f, -0.5f, 0.309017f, 0.809017f, -0.809017f,
  0.5f, 0.309017f, -0.809017f, 0.5f, -0.309017f
};

// Per-CHANNEL descriptor (768 entries): ((127+deg)<<23) | (src<<3) | phase.
struct DescTab768 { unsigned v[768]; };
static constexpr DescTab768 make_desc768() {
    DescTab768 t{};
    for (int c = 0; c < 768; ++c) {
        int deg, src, ph;
        if      (c < 48)  { deg = c / 3;               src = 21 + c % 3;        ph = 0; }
        else if (c < 96)  { int cc = c - 48;  deg = cc / 3;  src = 21 + cc % 3; ph = 1; }
        else if (c < 432) { int cc = c - 96;  deg = cc / 21; src = cc % 21;     ph = 0; }
        else              { int cc = c - 432; deg = cc / 21; src = cc % 21;     ph = 1; }
        t.v[c] = ((unsigned)(127 + deg) << 23) | ((unsigned)src << 3) | (unsigned)ph;
    }
    return t;
}
__constant__ DescTab768 cDesc = make_desc768();

struct Moments { float t_mean, t_var, r_var; };

__device__ inline Moments frustum_moments(float t0, float t1, float radius) {
    float mu  = 0.5f * (t0 + t1);
    float hw  = 0.5f * (t1 - t0);
    float mu2 = mu * mu, hw2 = hw * hw;
    float denom = 3.0f * mu2 + hw2;
    float inv_d = 1.0f / denom;
    float hw4 = hw2 * hw2;
    Moments m;
    m.t_mean = mu + 2.0f * mu * hw2 * inv_d;
    m.t_var  = hw2 * (1.0f / 3.0f)
             - (4.0f / 15.0f) * (hw4 * (12.0f * mu2 - hw2) * inv_d * inv_d);
    m.r_var  = radius * radius *
               (0.25f * mu2 + (5.0f / 12.0f) * hw2 - (4.0f / 15.0f) * hw4 * inv_d);
    return m;
}

// Emit 4 consecutive channels (one float4) from a per-lane descriptor quad.
__device__ inline void emit4(uint4 d, const char* __restrict__ rowXV, float* __restrict__ o) {
    vfloat4 v;
    {
        unsigned wd = d.x;
        float sf = __uint_as_float(wd & 0xFF800000u);                 // 2^deg
        float2 xv = *reinterpret_cast<const float2*>(rowXV + (wd & 0xF8u));
        float e  = __builtin_amdgcn_exp2f(xv.y * (sf * sf));          // exp(-0.5*var*4^deg)
        float ph = (float)(wd & 1u) * 0.25f;
        v.x = e * __builtin_amdgcn_sinf(__builtin_amdgcn_fractf(xv.x * sf + ph));
    }
    {
        unsigned wd = d.y;
        float sf = __uint_as_float(wd & 0xFF800000u);
        float2 xv = *reinterpret_cast<const float2*>(rowXV + (wd & 0xF8u));
        float e  = __builtin_amdgcn_exp2f(xv.y * (sf * sf));
        float ph = (float)(wd & 1u) * 0.25f;
        v.y = e * __builtin_amdgcn_sinf(__builtin_amdgcn_fractf(xv.x * sf + ph));
    }
    {
        unsigned wd = d.z;
        float sf = __uint_as_float(wd & 0xFF800000u);
        float2 xv = *reinterpret_cast<const float2*>(rowXV + (wd & 0xF8u));
        float e  = __builtin_amdgcn_exp2f(xv.y * (sf * sf));
        float ph = (float)(wd & 1u) * 0.25f;
        v.z = e * __builtin_amdgcn_sinf(__builtin_amdgcn_fractf(xv.x * sf + ph));
    }
    {
        unsigned wd = d.w;
        float sf = __uint_as_float(wd & 0xFF800000u);
        float2 xv = *reinterpret_cast<const float2*>(rowXV + (wd & 0xF8u));
        float e  = __builtin_amdgcn_exp2f(xv.y * (sf * sf));
        float ph = (float)(wd & 1u) * 0.25f;
        v.w = e * __builtin_amdgcn_sinf(__builtin_amdgcn_fractf(xv.x * sf + ph));
    }
    __builtin_nontemporal_store(v, reinterpret_cast<vfloat4*>(o));
}

// Barrier-free: each wave owns samples [16*wid, 16*wid+16) end-to-end.
// 4 lanes per sample compute fg + bg-core (redundant) and split the 21
// projections 6/5/5/5. LDS rows are wave-private -> no __syncthreads at all.
__global__ __launch_bounds__(256, 4) void mipnerf_enc(
    const float* __restrict__ ray_o,
    const float* __restrict__ ray_d,
    const float* __restrict__ fgz,
    const float* __restrict__ bgz,
    const float* __restrict__ radii,
    float* __restrict__ out)
{
    const int n    = blockIdx.x;
    const int tid  = threadIdx.x;
    const int lane = tid & 63;
    const int wid  = tid >> 6;            // wave id 0..3
    const int sub  = lane & 3;            // role within 4-lane sample group
    const int s    = wid * 16 + (lane >> 2);  // this group's sample

    // Per-sample sources: 24 pairs (X = x/2pi, V = -0.5*log2e * var), stride 50 floats.
    __shared__ float sXV[NS * 50];

    const float ox = ray_o[3 * n + 0], oy = ray_o[3 * n + 1], oz = ray_o[3 * n + 2];
    const float dx = ray_d[3 * n + 0], dy = ray_d[3 * n + 1], dz = ray_d[3 * n + 2];
    const float rad = radii[n];
    const float dm = fmaxf(1e-8f, dx * dx + dy * dy + dz * dz);
    const float inv_dm = 1.0f / dm;

    { // ---- FG (diagonal covariance): sub 0..2 each produce one channel ----
        float t0 = fgz[(NS + 1) * n + s];
        float t1 = fgz[(NS + 1) * n + s + 1];
        Moments mm = frustum_moments(t0, t1, rad);
        if (sub < 3) {
            float d3 = (sub == 0) ? dx : ((sub == 1) ? dy : dz);
            float o3 = (sub == 0) ? ox : ((sub == 1) ? oy : oz);
            float m  = o3 + d3 * mm.t_mean;
            float dd = d3 * d3;
            float cd = mm.t_var * dd + mm.r_var * (1.0f - dd * inv_dm);
            sXV[s * 50 + 2 * (21 + sub) + 0] = m  * INV2PI;
            sXV[s * 50 + 2 * (21 + sub) + 1] = cd * NEGHL2E;
        }
    }
    { // ---- BG core (redundant per lane) + projections split across subs ----
        float t0 = bgz[(NS + 1) * n + s];
        float t1 = bgz[(NS + 1) * n + s + 1];
        Moments mm = frustum_moments(t0, t1, rad);
        float x0 = ox + dx * mm.t_mean;
        float x1 = oy + dy * mm.t_mean;
        float x2 = oz + dz * mm.t_mean;
        float a  = mm.t_var - mm.r_var * inv_dm;   // C = a*ddT + rv*I
        float rv = mm.r_var;
        float rn2 = x0 * x0 + x1 * x1 + x2 * x2;
        float rn  = sqrtf(rn2);
        float nn  = rn + 1e-6f;
        float inn = 1.0f / nn;
        float g   = (2.0f * nn - 1.0f) * inn * inn;       // (2 - 1/n)/n
        float gp  = 2.0f * (1.0f - nn) * inn * inn * inn; // g'(n)
        float h   = gp / rn;                              // J = g*I + h*x*xT
        float xd  = x0 * dx + x1 * dy + x2 * dz;
        float hxd = h * xd;
        float u0 = g * dx + hxd * x0;                     // u = J d
        float u1 = g * dy + hxd * x1;
        float u2 = g * dz + hxd * x2;
        float jw = 2.0f * g * h + h * h * rn2;            // J^2 = g^2 I + w x xT
        float c1 = a, c2 = rv * g * g, c3 = rv * jw;
        #pragma unroll
        for (int j = 0; j < 6; ++j) {
            int k = sub + 4 * j;           // sub0: 6 cols, sub1..3: 5 cols
            if (k < 21) {
                const float p0 = c_P[k], p1 = c_P[21 + k], p2 = c_P[42 + k];
                float dpx = p0 * x0 + p1 * x1 + p2 * x2;
                float dpu = p0 * u0 + p1 * u1 + p2 * u2;
                float pp  = p0 * p0 + p1 * p1 + p2 * p2;
                float y   = g * dpx;
                float yv  = c1 * dpu * dpu + c2 * pp + c3 * dpx * dpx;
                sXV[s * 50 + 2 * k + 0] = y  * INV2PI;
                sXV[s * 50 + 2 * k + 1] = yv * NEGHL2E;
            }
        }
    }

    // Wave-private LDS handoff: wait for this wave's own LDS writes, no barrier.
    asm volatile("s_waitcnt lgkmcnt(0)" ::: "memory");

    // Descriptors straight from __constant__ (L2-resident after first block).
    const uint4* cD4 = reinterpret_cast<const uint4*>(cDesc.v);
    const uint4 d0 = cD4[lane];        // channels   0 + lane*4 .. +3
    const uint4 d1 = cD4[64 + lane];   // channels 256 + lane*4 .. +3
    const uint4 d2 = cD4[128 + lane];  // channels 512 + lane*4 .. +3

    // ---- Emit: strictly-linear per-wave store stream (proven 5.4 TB/s). ----
    float* __restrict__ outp = out + (size_t)n * (NS * 768);

    for (int ss = 0; ss < 16; ++ss) {
        const int se = wid * 16 + ss;
        const char* rowXV = reinterpret_cast<const char*>(&sXV[se * 50]);
        float* orow = outp + se * 768 + lane * 4;
        emit4(d0, rowXV, orow);
        emit4(d1, rowXV, orow + 256);
        emit4(d2, rowXV, orow + 512);
    }
}

extern "C" void kernel_launch(void* const* d_in, const int* in_sizes, int n_in,
                              void* d_out, int out_size, void* d_ws, size_t ws_size,
                              hipStream_t stream) {
    const float* ray_o = (const float*)d_in[0];
    const float* ray_d = (const float*)d_in[1];
    const float* fgz   = (const float*)d_in[2];
    const float* bgz   = (const float*)d_in[3];
    const float* radii = (const float*)d_in[4];
    float* out = (float*)d_out;
    const int N = in_sizes[0] / 3;   // 2048 rays
    mipnerf_enc<<<N, 256, 0, stream>>>(ray_o, ray_d, fgz, bgz, radii, out);
}